// Round 7
// baseline (348.660 us; speedup 1.0000x reference)
//
#include <hip/hip_runtime.h>
#include <stdint.h>

#define P 2048
#define R 65536
#define DD 512
#define BM 256
#define BN 128
#define BK 64
#define NT (DD / BK)   // 8 K-tiles

typedef __attribute__((ext_vector_type(8))) short short8;
typedef __attribute__((ext_vector_type(4))) float f32x4;

__device__ inline unsigned short f2bf(float f) {
  unsigned int u = __float_as_uint(f);
  u += 0x7fffu + ((u >> 16) & 1u);   // round-to-nearest-even
  return (unsigned short)(u >> 16);
}

__device__ inline void gload_lds16(const void* g, void* l) {
  __builtin_amdgcn_global_load_lds(
      (const __attribute__((address_space(1))) unsigned int*)g,
      (__attribute__((address_space(3))) unsigned int*)l,
      16, 0, 0);
}

// ---- kernel 1: fp32 -> bf16 conversion + fp32 row norms; one wave per row,
//      grid-stride (2048 blocks, ~8 rows/wave) ----
__global__ __launch_bounds__(256) void k_convert(
    const float* __restrict__ pred, const float* __restrict__ cand,
    unsigned short* __restrict__ Abf, unsigned short* __restrict__ Bbf,
    float* __restrict__ nx, float* __restrict__ ny,
    unsigned int* __restrict__ minp)
{
  if (blockIdx.x == 0 && threadIdx.x == 0) *minp = 0x7f800000u; // +inf bits
  const int lane = threadIdx.x & 63;
  const int wv   = (blockIdx.x << 2) | (threadIdx.x >> 6);
  const int nw   = gridDim.x << 2;
  for (int gw = wv; gw < P + R; gw += nw) {
    const float* src; unsigned short* dst; float* np;
    if (gw < P) { src = pred + (size_t)gw * DD; dst = Abf + (size_t)gw * DD; np = nx + gw; }
    else { int r = gw - P; src = cand + (size_t)r * DD; dst = Bbf + (size_t)r * DD; np = ny + r; }
    const float4* s4 = ((const float4*)src) + lane * 2;
    float4 v0 = s4[0], v1 = s4[1];
    float ss = v0.x*v0.x + v0.y*v0.y + v0.z*v0.z + v0.w*v0.w
             + v1.x*v1.x + v1.y*v1.y + v1.z*v1.z + v1.w*v1.w;
    union { unsigned short h[8]; uint4 v; } pk;
    pk.h[0]=f2bf(v0.x); pk.h[1]=f2bf(v0.y); pk.h[2]=f2bf(v0.z); pk.h[3]=f2bf(v0.w);
    pk.h[4]=f2bf(v1.x); pk.h[5]=f2bf(v1.y); pk.h[6]=f2bf(v1.z); pk.h[7]=f2bf(v1.w);
    *(uint4*)(dst + (size_t)lane * 8) = pk.v;
    #pragma unroll
    for (int off = 32; off; off >>= 1) ss += __shfl_down(ss, off, 64);
    if (lane == 0) *np = ss;
  }
}

// ---- kernel 2: 256x128 bf16 MFMA tile GEMM (A·B^T), BK=64, 4 waves (2Mx2N,
//      wave tile 128x64 = round-1 read economy), 16x16x32 MFMA (measured
//      conflict-free swizzle), *** SINGLE-buffer LDS (48 KB) -> 2 blocks/CU,
//      two INDEPENDENT barrier domains per CU ***: one block's stage/drain/
//      barrier phase overlaps the other block's read+MFMA phase (cross-block
//      anti-phase skew — the overlap that barrier-locked 1-block/CU configs
//      of rounds 1-6 could never achieve). s_sleep parity seed breaks initial
//      symmetry. setprio (T5), XCD swizzle (T1), fused min epilogue.
//
// LDS: As[256][64], Bs[128][64] bf16; 16B-chunks of each row stored permuted:
// stored_chunk = data_chunk ^ (row & 7) — round-1's measured-zero-conflict
// layout — applied via the GLOBAL source address (linear gload_lds dest +
// inverse-swizzled per-lane source; rule #21).
//
// Per-tile schedule (single buffer):
//   compute tile T (B-frags hoisted, 2 M-halves; compiler-scheduled waits)
//   if T<NT-1:  s_barrier            [all waves done READING the buffer]
//               STAGE(T+1)           [12 gload_lds overwrite the buffer]
//               s_waitcnt vmcnt(0)   [my 12 loads landed; ~400cy, hidden by
//                                     the co-resident block's compute]
//               s_barrier            [everyone's loads landed]
__global__ __launch_bounds__(256, 2) void k_gemm_min(
    const unsigned short* __restrict__ Abf, const unsigned short* __restrict__ Bbf,
    const float* __restrict__ nx, const float* __restrict__ ny,
    unsigned int* __restrict__ minp)
{
  __shared__ __align__(16) unsigned short As[BM * BK];   // 32 KB
  __shared__ __align__(16) unsigned short Bs[BN * BK];   // 16 KB
  __shared__ float wmin[4];

  const int tid  = threadIdx.x;
  const int wave = tid >> 6;          // 0..3
  const int lane = tid & 63;

  // XCD-aware bijective remap: 4096 blocks, 8 XCDs, 512 contiguous per XCD.
  const int raw = blockIdx.x;
  const int wg  = (raw & 7) * 512 + (raw >> 3);
  const int by  = wg & 7;             // pred tile fast -> 8 adjacent wg share cand tile
  const int bx  = wg >> 3;            // cand tile 0..511
  const int rowA0 = by * BM, rowB0 = bx * BN;
  const int wr = wave >> 1;           // 0..1 : M half   (wave tile 128x64)
  const int wc = wave & 1;            // 0..1 : N half

  f32x4 zero = {0.f, 0.f, 0.f, 0.f};
  f32x4 acc[8][4];
  #pragma unroll
  for (int i = 0; i < 8; ++i)
    #pragma unroll
    for (int j = 0; j < 4; ++j) acc[i][j] = zero;

  // staging: A = 32 KB = 32 groups (8 rows x 64 cols, 1 KB); wave stages
  // groups wave*8 .. wave*8+7. B = 16 KB = 16 groups; wave stages wave*4..+3.
  // lane L -> local row L>>3, stored chunk L&7, source data chunk (L&7)^(L>>3).
  const int rloc = lane >> 3;
  const int cswz = (lane & 7) ^ rloc;
  const unsigned short* gAb = Abf + (size_t)(rowA0 + wave * 64 + rloc) * DD + cswz * 8;
  const unsigned short* gBb = Bbf + (size_t)(rowB0 + wave * 32 + rloc) * DD + cswz * 8;
  unsigned short* lAb = &As[(wave * 8) * 512];
  unsigned short* lBb = &Bs[(wave * 4) * 512];

  // incremental-pointer staging (unroll 1) keeps address VGPRs ~4 instead of 24
#define STAGE(kt) do {                                                   \
    const unsigned short* _pa = gAb + (kt) * BK; unsigned short* _la = lAb; \
    _Pragma("unroll 1")                                                  \
    for (int _t = 0; _t < 8; ++_t) {                                     \
      gload_lds16(_pa, _la); _pa += 8 * DD; _la += 512; }                \
    const unsigned short* _pb = gBb + (kt) * BK; unsigned short* _lb = lBb; \
    _Pragma("unroll 1")                                                  \
    for (int _t = 0; _t < 4; ++_t) {                                     \
      gload_lds16(_pb, _lb); _pb += 8 * DD; _lb += 512; }                \
  } while (0)

  // fragment read geometry (16x16x32, round-1 proven conflict-free).
  // A frag i: row wr*128 + i*16 + m; B frag j: row wc*64 + j*16 + m;
  // k-chunk (h*4+quad) stored at chunk ^ (m&7).
  const int m = lane & 15, quad = lane >> 4, mb = m & 7;
  const int aRow0 = (wr * 128 + m) * BK;
  const int bRow0 = (wc * 64  + m) * BK;
  const int sw0 = ((quad    ) ^ mb) * 8;
  const int sw1 = ((quad + 4) ^ mb) * 8;

  // parity seed: half the blocks start ~512cy late so co-resident pairs
  // begin anti-phase (cost: one-time 0.2us; benefit: stage/compute overlap)
  if ((raw >> 3) & 1) __builtin_amdgcn_s_sleep(8);

  STAGE(0);
  asm volatile("s_waitcnt vmcnt(0)" ::: "memory");
  __builtin_amdgcn_s_barrier();

  #pragma unroll 1
  for (int T = 0; T < NT; ++T) {
    // ---- compute tile T (round-1 body; compiler schedules lgkm waits) ----
    short8 bfr[4][2];
    #pragma unroll
    for (int j = 0; j < 4; ++j) {
      const unsigned short* bp = Bs + bRow0 + j * 16 * BK;
      bfr[j][0] = *(const short8*)(bp + sw0);
      bfr[j][1] = *(const short8*)(bp + sw1);
    }
    #pragma unroll
    for (int mh = 0; mh < 2; ++mh) {
      short8 af[4][2];
      #pragma unroll
      for (int i = 0; i < 4; ++i) {
        const unsigned short* ap = As + aRow0 + (mh * 4 + i) * 16 * BK;
        af[i][0] = *(const short8*)(ap + sw0);
        af[i][1] = *(const short8*)(ap + sw1);
      }
      __builtin_amdgcn_s_setprio(1);
      #pragma unroll
      for (int i = 0; i < 4; ++i)
        #pragma unroll
        for (int j = 0; j < 4; ++j) {
          acc[mh*4+i][j] = __builtin_amdgcn_mfma_f32_16x16x32_bf16(af[i][0], bfr[j][0], acc[mh*4+i][j], 0, 0, 0);
          acc[mh*4+i][j] = __builtin_amdgcn_mfma_f32_16x16x32_bf16(af[i][1], bfr[j][1], acc[mh*4+i][j], 0, 0, 0);
        }
      __builtin_amdgcn_s_setprio(0);
    }

    // ---- stage tile T+1 over the single buffer ----
    if (T + 1 < NT) {
      __builtin_amdgcn_s_barrier();       // all waves done reading buffer
      STAGE(T + 1);
      asm volatile("s_waitcnt vmcnt(0)" ::: "memory");  // my loads landed
      __builtin_amdgcn_s_barrier();       // everyone's loads landed
    }
  }
#undef STAGE

  // epilogue: d^2 = ||x||^2 + ||y||^2 - 2*dot ; C/D layout col=lane&15, row=quad*4+reg
  float lmin = 3.4e38f;
  #pragma unroll
  for (int i = 0; i < 8; ++i) {
    const int mbase = rowA0 + wr * 128 + i * 16 + quad * 4;
    float4 nxv = *(const float4*)(nx + mbase);
    #pragma unroll
    for (int j = 0; j < 4; ++j) {
      const int n = rowB0 + wc * 64 + j * 16 + m;
      const float nyv = ny[n];
      f32x4 a = acc[i][j];
      lmin = fminf(lmin, nxv.x + nyv - 2.0f * a[0]);
      lmin = fminf(lmin, nxv.y + nyv - 2.0f * a[1]);
      lmin = fminf(lmin, nxv.z + nyv - 2.0f * a[2]);
      lmin = fminf(lmin, nxv.w + nyv - 2.0f * a[3]);
    }
  }
  #pragma unroll
  for (int off = 32; off; off >>= 1) lmin = fminf(lmin, __shfl_down(lmin, off, 64));
  if (lane == 0) wmin[wave] = lmin;
  __syncthreads();
  if (tid == 0) {
    float mn = fminf(fminf(wmin[0], wmin[1]), fminf(wmin[2], wmin[3]));
    atomicMin(minp, __float_as_uint(fmaxf(mn, 0.0f)));
  }
}

// ---- fallback (only if ws too small): exact fp32 brute force ----
__global__ __launch_bounds__(64) void k_initmin(unsigned int* minp) {
  if (threadIdx.x == 0) *minp = 0x7f800000u;
}

__global__ __launch_bounds__(256) void k_brute(
    const float* __restrict__ pred, const float* __restrict__ cand,
    unsigned int* __restrict__ minp)
{
  __shared__ float yrow[DD];
  __shared__ float wm[4];
  const int c = blockIdx.x;
  for (int i = threadIdx.x; i < DD; i += 256) yrow[i] = cand[(size_t)c * DD + i];
  __syncthreads();
  float lmin = 3.4e38f;
  for (int p = threadIdx.x; p < P; p += 256) {
    const float* xp = pred + (size_t)p * DD;
    float s = 0.f;
    for (int k = 0; k < DD; ++k) { float d = xp[k] - yrow[k]; s = fmaf(d, d, s); }
    lmin = fminf(lmin, s);
  }
  #pragma unroll
  for (int off = 32; off; off >>= 1) lmin = fminf(lmin, __shfl_down(lmin, off, 64));
  if ((threadIdx.x & 63) == 0) wm[threadIdx.x >> 6] = lmin;
  __syncthreads();
  if (threadIdx.x == 0) {
    float mn = fminf(fminf(wm[0], wm[1]), fminf(wm[2], wm[3]));
    atomicMin(minp, __float_as_uint(fmaxf(mn, 0.0f)));
  }
}

__global__ __launch_bounds__(64) void k_finalize(const unsigned int* minp, float* out) {
  if (threadIdx.x == 0) out[0] = sqrtf(__uint_as_float(*minp));
}

extern "C" void kernel_launch(void* const* d_in, const int* in_sizes, int n_in,
                              void* d_out, int out_size, void* d_ws, size_t ws_size,
                              hipStream_t stream) {
  const float* pred = (const float*)d_in[0];
  const float* cand = (const float*)d_in[1];
  float* out = (float*)d_out;

  // ws layout: [0] min-bits | +16 floats: nx[2048] | ny[65536] | Abf bf16[2048*512] | Bbf bf16[65536*512]
  unsigned int* minp = (unsigned int*)d_ws;
  float* wsf = (float*)d_ws;
  float* nx = wsf + 16;
  float* ny = nx + P;
  unsigned short* Abf = (unsigned short*)(ny + R);
  unsigned short* Bbf = Abf + (size_t)P * DD;
  const size_t need = (size_t)(16 + P + R) * 4 + ((size_t)P * DD + (size_t)R * DD) * 2;

  if (ws_size >= need) {
    k_convert<<<2048, 256, 0, stream>>>(pred, cand, Abf, Bbf, nx, ny, minp);
    k_gemm_min<<<(P / BM) * (R / BN), 256, 0, stream>>>(Abf, Bbf, nx, ny, minp);
  } else {
    k_initmin<<<1, 64, 0, stream>>>(minp);
    k_brute<<<R, 256, 0, stream>>>(pred, cand, minp);
  }
  k_finalize<<<1, 64, 0, stream>>>(minp, out);
}